// Round 1
// baseline (190.015 us; speedup 1.0000x reference)
//
#include <hip/hip_runtime.h>
#include <stdint.h>

#define CCH 64
#define HWPIX 65536
#define NBINS 256

// ws layout (float slots):
// [0    .. 1023] : dominant bins, int32, B*C entries
// [1024 .. 5119] : WcolT[o*64+c] = W1[o*64+c] * inv1[o]
// [5120 .. 5183] : base_pre[o] = (S[o]+b1[o])*inv1[o] + (beta1[o]-mean1[o]*inv1[o])
// [5184 .. 5247] : w2[o]
// [5248 .. 5251] : scalars {inv2, beta2p, b2, s_empty}

__global__ __launch_bounds__(64) void precomp_kernel(
    const float* __restrict__ w1, const float* __restrict__ b1,
    const float* __restrict__ g1, const float* __restrict__ be1,
    const float* __restrict__ m1, const float* __restrict__ v1,
    const float* __restrict__ w2, const float* __restrict__ b2,
    const float* __restrict__ g2, const float* __restrict__ be2,
    const float* __restrict__ m2, const float* __restrict__ v2,
    float* __restrict__ ws)
{
    int o = threadIdx.x;  // 0..63
    float inv1 = g1[o] * rsqrtf(v1[o] + 1e-5f);
    float S = 0.f;
    for (int c = 0; c < CCH; ++c) S += w1[o * CCH + c];
    float beta1p = be1[o] - m1[o] * inv1;
    float base_pre = (S + b1[o]) * inv1 + beta1p;
    for (int c = 0; c < CCH; ++c) ws[1024 + o * CCH + c] = w1[o * CCH + c] * inv1;
    ws[5120 + o] = base_pre;
    float w2o = w2[o];
    ws[5184 + o] = w2o;
    // reduce t_base = sum_o relu(base_pre)*w2  across the single wave
    float t = fmaxf(base_pre, 0.f) * w2o;
    #pragma unroll
    for (int off = 32; off > 0; off >>= 1) t += __shfl_down(t, off, 64);
    if (o == 0) {
        float inv2 = g2[0] * rsqrtf(v2[0] + 1e-5f);
        float beta2p = be2[0] - m2[0] * inv2;
        float z = (t + b2[0]) * inv2 + beta2p;
        ws[5248] = inv2;
        ws[5249] = beta2p;
        ws[5250] = b2[0];
        ws[5251] = 1.f / (1.f + expf(-z));
    }
}

// One block per (b,c) image: 256-bin histogram + first-max argmax.
__global__ __launch_bounds__(256) void hist_kernel(
    const float* __restrict__ x, int* __restrict__ dom)
{
    __shared__ unsigned h[4][NBINS];            // wave-private sub-histograms
    __shared__ unsigned long long red[NBINS];
    int tid = threadIdx.x;
    const float4* xp = (const float4*)(x + (size_t)blockIdx.x * HWPIX);

    for (int i = tid; i < 4 * NBINS; i += 256) ((unsigned*)h)[i] = 0;
    __syncthreads();

    unsigned* hmine = h[tid >> 6];
    const float scale = 256.0f / 255.0f;   // same f32 value JAX uses
    #pragma unroll 4
    for (int t = 0; t < HWPIX / 4 / 256; ++t) {
        float4 v = xp[t * 256 + tid];
        float vv[4] = {v.x, v.y, v.z, v.w};
        #pragma unroll
        for (int j = 0; j < 4; ++j) {
            float f = vv[j];
            if (f >= 0.f && f <= 255.f) {       // histc ignores out-of-range
                int bi = (int)(f * scale);      // trunc == JAX astype(int32), f>=0
                bi = bi > NBINS - 1 ? NBINS - 1 : bi;
                atomicAdd(&hmine[bi], 1u);
            }
        }
    }
    __syncthreads();

    unsigned cnt = h[0][tid] + h[1][tid] + h[2][tid] + h[3][tid];
    // pack so max(key) == (max count, smallest bin index)  -> jnp.argmax tie rule
    red[tid] = ((unsigned long long)cnt << 32) | (unsigned)(NBINS - 1 - tid);
    __syncthreads();
    #pragma unroll
    for (int s = 128; s > 0; s >>= 1) {
        if (tid < s) {
            unsigned long long a = red[tid], b = red[tid + s];
            red[tid] = a > b ? a : b;
        }
        __syncthreads();
    }
    if (tid == 0) dom[blockIdx.x] = (NBINS - 1) - (int)(red[0] & 0xffffffffu);
}

// Thread-per-pixel fused mask + sparse conv correction + output scale.
__global__ __launch_bounds__(256) void main_kernel(
    const float* __restrict__ x, const float* __restrict__ ws,
    const int* __restrict__ dom, float* __restrict__ out)
{
    __shared__ float WcolT[CCH * CCH];   // 16 KiB
    __shared__ float bp_s[CCH];
    __shared__ float w2_s[CCH];
    __shared__ int   dom_s[CCH];
    __shared__ float sc[4];

    int tid = threadIdx.x;
    int b = blockIdx.x >> 8;                       // 256 blocks per batch image
    int hw = ((blockIdx.x & 255) << 8) | tid;      // pixel within image

    for (int i = tid; i < CCH * CCH; i += 256) WcolT[i] = ws[1024 + i];
    if (tid < CCH) {
        bp_s[tid]  = ws[5120 + tid];
        w2_s[tid]  = ws[5184 + tid];
        dom_s[tid] = dom[b * CCH + tid];
    }
    if (tid < 4) sc[tid] = ws[5248 + tid];
    __syncthreads();

    const float* xb = x + ((size_t)b << 22);       // b * 64 * 65536
    float vx[CCH];
    #pragma unroll
    for (int c = 0; c < CCH; ++c) vx[c] = xb[((size_t)c << 16) + hw];

    unsigned long long m = 0ull;
    #pragma unroll
    for (int c = 0; c < CCH; ++c)
        m |= (unsigned long long)((int)floorf(vx[c]) == dom_s[c]) << c;

    float s;
    if (m == 0ull) {
        s = sc[3];                                  // precomputed sigmoid
    } else {
        float t = 0.f;
        for (int o = 0; o < CCH; ++o) {
            float acc = bp_s[o];
            unsigned long long mm = m;
            const float* row = &WcolT[o << 6];
            while (mm) {
                int c = __builtin_ctzll(mm);
                mm &= mm - 1;
                acc -= row[c];
            }
            t += fmaxf(acc, 0.f) * w2_s[o];
        }
        float z = (t + sc[2]) * sc[0] + sc[1];
        s = 1.f / (1.f + expf(-z));
    }

    float* ob = out + ((size_t)b << 22);
    #pragma unroll
    for (int c = 0; c < CCH; ++c) ob[((size_t)c << 16) + hw] = vx[c] * s;
}

extern "C" void kernel_launch(void* const* d_in, const int* in_sizes, int n_in,
                              void* d_out, int out_size, void* d_ws, size_t ws_size,
                              hipStream_t stream) {
    const float* x   = (const float*)d_in[0];
    const float* w1  = (const float*)d_in[1];
    const float* b1  = (const float*)d_in[2];
    const float* g1  = (const float*)d_in[3];
    const float* be1 = (const float*)d_in[4];
    const float* m1  = (const float*)d_in[5];
    const float* v1  = (const float*)d_in[6];
    const float* w2  = (const float*)d_in[7];
    const float* b2  = (const float*)d_in[8];
    const float* g2  = (const float*)d_in[9];
    const float* be2 = (const float*)d_in[10];
    const float* m2  = (const float*)d_in[11];
    const float* v2  = (const float*)d_in[12];

    float* ws  = (float*)d_ws;
    int*   dom = (int*)d_ws;                       // aliases ws[0..1023]
    float* outp = (float*)d_out;

    int B = in_sizes[0] / (CCH * HWPIX);           // 16

    precomp_kernel<<<1, 64, 0, stream>>>(w1, b1, g1, be1, m1, v1,
                                         w2, b2, g2, be2, m2, v2, ws);
    hist_kernel<<<B * CCH, 256, 0, stream>>>(x, dom);
    main_kernel<<<B * (HWPIX / 256), 256, 0, stream>>>(x, ws, dom, outp);
}